// Round 14
// baseline (127.338 us; speedup 1.0000x reference)
//
#include <hip/hip_runtime.h>
#include <stdint.h>

// S=4096, D=64.  out = (t * floor(t*rr)/R) @ V,  t = (QK^T*8) * dropout_keep/0.9
// R14: R11 skeleton (JT=64, DMA staging, fragment-major LDS, dbuf kb AND vb,
// 2 barriers/tile) + REAL pipelining with airtight ordering:
//  - every vmem group separated by asm memory clobbers (R13 died because
//    plain u-loads were hoisted across a DMA, permuting the vmcnt queue)
//  - u(t) packed at TOP of tile t (auto vmcnt(4), keeps DMAs(t) in flight)
//  - gate vmcnt(8) keeps exactly tile t+1's 8 prefetch ops
//  - NCHUNK=16 -> 1024 blocks fills the 3-blocks/CU LDS capacity.

#define S 4096
#define D 64
#define NCHUNK 16             // grid = 64 i-blocks * 16 chunks = 1024 blocks
#define JCHUNK (S / NCHUNK)   // 256
#define JT 64
#define NTILES (JCHUNK / JT)  // 4
#define LDP 72                // pb pitch in shorts
#define KSCALE (8.0f / 0.9f)

typedef float f32x4 __attribute__((ext_vector_type(4)));
typedef short s16x8 __attribute__((ext_vector_type(8)));
typedef unsigned short u16x4 __attribute__((ext_vector_type(4)));
typedef const __attribute__((address_space(1))) unsigned g_u32;
typedef __attribute__((address_space(3))) unsigned lds_u32;

#define CLOBBER() __asm__ volatile("" ::: "memory")

__device__ inline unsigned short f2bf(float f) {
    union { float f; unsigned u; } v; v.f = f;
    unsigned r = v.u + 0x7fffu + ((v.u >> 16) & 1u);
    return (unsigned short)(r >> 16);
}

// ---- prep: Q->bf16, K->bf16*KSCALE (blocks 0..511), V->V^T (512..575) ----
__global__ void prep_all(const float* __restrict__ Q,
                         const float* __restrict__ Kf,
                         const float* __restrict__ V,
                         short* __restrict__ Qbf, short* __restrict__ Kbf,
                         short* __restrict__ VTbf, int* __restrict__ sumr) {
    __shared__ short tile[64 * 68];
    const int b   = blockIdx.x;
    const int tid = threadIdx.x;
    if (b == 0 && tid == 0) *sumr = 0;

    if (b < 512) {
        const int idx = b * 256 + tid;               // 131072 float4 slots
        if (idx < 65536) {
            float4 v = ((const float4*)Q)[idx];
            u16x4 o; o[0] = f2bf(v.x); o[1] = f2bf(v.y); o[2] = f2bf(v.z); o[3] = f2bf(v.w);
            ((u16x4*)Qbf)[idx] = o;
        } else {
            const int k = idx - 65536;
            float4 v = ((const float4*)Kf)[k];
            u16x4 o; o[0] = f2bf(v.x * KSCALE); o[1] = f2bf(v.y * KSCALE);
                     o[2] = f2bf(v.z * KSCALE); o[3] = f2bf(v.w * KSCALE);
            ((u16x4*)Kbf)[k] = o;
        }
    } else {
        const int j0 = (b - 512) * 64;
#pragma unroll
        for (int it = 0; it < 4; ++it) {
            const int f4 = tid + it * 256;
            const int row = f4 >> 4, c4 = (f4 & 15) * 4;
            float4 v = *(const float4*)&V[(size_t)(j0 + row) * D + c4];
            tile[(c4 + 0) * 68 + row] = (short)f2bf(v.x);
            tile[(c4 + 1) * 68 + row] = (short)f2bf(v.y);
            tile[(c4 + 2) * 68 + row] = (short)f2bf(v.z);
            tile[(c4 + 3) * 68 + row] = (short)f2bf(v.w);
        }
        __syncthreads();
#pragma unroll
        for (int it = 0; it < 4; ++it) {
            const int f4 = tid + it * 256;
            const int d = f4 >> 4, o4 = (f4 & 15) * 4;
            u16x4 w = *(const u16x4*)&tile[d * 68 + o4];
            *(u16x4*)&VTbf[(size_t)d * S + j0 + o4] = w;
        }
    }
}

// ---- main ----
__launch_bounds__(256, 3)
__global__ void fused_main(const short* __restrict__ Qbf,
                           const short* __restrict__ Kbf,
                           const short* __restrict__ VTbf,
                           const float* __restrict__ Ud,
                           const float* __restrict__ RR,
                           float* __restrict__ Opart,            // [NCHUNK][S][D]
                           int* __restrict__ sumr)
{
    __shared__ short kb[2][8 * 512];     // K tile 64x64, fragment-major, dbuf
    __shared__ short vb[2][8 * 512];     // V^T tile 64x64, fragment-major, dbuf
    __shared__ short pb[4 * 16 * LDP];   // per-wave P relayout
    __shared__ int red[4];

    const int tid  = threadIdx.x;
    const int w    = tid >> 6;
    const int lane = tid & 63;
    const int quad = lane >> 4;
    const int n16  = lane & 15;

    const int ib  = blockIdx.x & 63;
    const int ic  = blockIdx.x >> 6;     // 0..NCHUNK-1
    const int i0w = ib * 64 + w * 16;
    const int jbase = ic * JCHUNK;

    const float* uwb = Ud + (size_t)i0w * S;

    s16x8 aQ[2];
#pragma unroll
    for (int ks = 0; ks < 2; ++ks)
        aQ[ks] = *(const s16x8*)&Qbf[(size_t)(i0w + n16) * D + ks * 32 + quad * 8];

    float rr[4];
#pragma unroll
    for (int rg = 0; rg < 4; ++rg) rr[rg] = RR[i0w + quad * 4 + rg];

    f32x4 accO[4];
#pragma unroll
    for (int ds = 0; ds < 4; ++ds) accO[ds] = (f32x4){0.f, 0.f, 0.f, 0.f};

    float lsum = 0.f;
    short* pw = pb + w * 16 * LDP;

    const int bsel  = quad * 4 + (n16 & 3);
    const int bidx0 = (n16 >> 2) * 4;

    const int e0 = w * 2, e1 = w * 2 + 1;   // this wave's 2 K-frags / 2 V-frags

    float4 un[4];   // u(t) raw values; loaded at tile t-1, packed at top of tile t

    // ---- prologue: tile 0 prefetch (u first, clobber, DMAs, clobber) ----
    {
        const int j0 = jbase;
#pragma unroll
        for (int q = 0; q < 4; ++q)
            un[q] = *(const float4*)&uwb[(size_t)(q * 4 + quad) * S + j0 + n16 * 4];
        CLOBBER();
        __builtin_amdgcn_global_load_lds(
            (g_u32*)&Kbf[(size_t)(j0 + (e0 >> 1) * 16 + n16) * D + (e0 & 1) * 32 + quad * 8],
            (lds_u32*)&kb[0][e0 * 512], 16, 0, 0);
        __builtin_amdgcn_global_load_lds(
            (g_u32*)&Kbf[(size_t)(j0 + (e1 >> 1) * 16 + n16) * D + (e1 & 1) * 32 + quad * 8],
            (lds_u32*)&kb[0][e1 * 512], 16, 0, 0);
        __builtin_amdgcn_global_load_lds(
            (g_u32*)&VTbf[(size_t)((e0 & 3) * 16 + n16) * S + j0 + (e0 >> 2) * 32 + quad * 8],
            (lds_u32*)&vb[0][e0 * 512], 16, 0, 0);
        __builtin_amdgcn_global_load_lds(
            (g_u32*)&VTbf[(size_t)((e1 & 3) * 16 + n16) * S + j0 + (e1 >> 2) * 32 + quad * 8],
            (lds_u32*)&vb[0][e1 * 512], 16, 0, 0);
        CLOBBER();
    }

#pragma unroll
    for (int jt = 0; jt < NTILES; ++jt) {
        const int bu = jt & 1;
        const int nb = bu ^ 1;
        const int j0 = jbase + jt * JT;
        const bool last = (jt + 1 == NTILES);

        // (p) pack u(t): auto-waitcnt drains only u(t) (vmcnt(4)); DMAs(t) stay
        unsigned um = 0;
#pragma unroll
        for (int q = 0; q < 4; ++q) {
            um |= (un[q].x >= 0.1f ? 1u : 0u) << (q * 4 + 0);
            um |= (un[q].y >= 0.1f ? 1u : 0u) << (q * 4 + 1);
            um |= (un[q].z >= 0.1f ? 1u : 0u) << (q * 4 + 2);
            um |= (un[q].w >= 0.1f ? 1u : 0u) << (q * 4 + 3);
        }

        // (a) tile t+1 prefetch: u loads, clobber, DMAs into [nb], clobber
        if (!last) {
            const int j1 = j0 + JT;
#pragma unroll
            for (int q = 0; q < 4; ++q)
                un[q] = *(const float4*)&uwb[(size_t)(q * 4 + quad) * S + j1 + n16 * 4];
            CLOBBER();
            __builtin_amdgcn_global_load_lds(
                (g_u32*)&Kbf[(size_t)(j1 + (e0 >> 1) * 16 + n16) * D + (e0 & 1) * 32 + quad * 8],
                (lds_u32*)&kb[nb][e0 * 512], 16, 0, 0);
            __builtin_amdgcn_global_load_lds(
                (g_u32*)&Kbf[(size_t)(j1 + (e1 >> 1) * 16 + n16) * D + (e1 & 1) * 32 + quad * 8],
                (lds_u32*)&kb[nb][e1 * 512], 16, 0, 0);
            __builtin_amdgcn_global_load_lds(
                (g_u32*)&VTbf[(size_t)((e0 & 3) * 16 + n16) * S + j1 + (e0 >> 2) * 32 + quad * 8],
                (lds_u32*)&vb[nb][e0 * 512], 16, 0, 0);
            __builtin_amdgcn_global_load_lds(
                (g_u32*)&VTbf[(size_t)((e1 & 3) * 16 + n16) * S + j1 + (e1 >> 2) * 32 + quad * 8],
                (lds_u32*)&vb[nb][e1 * 512], 16, 0, 0);
            CLOBBER();
        }

        // (b) gate: keep exactly tile t+1's 8 prefetch ops; drain DMAs(t)
        if (!last) { __asm__ volatile("s_waitcnt vmcnt(8)" ::: "memory"); }
        else       { __asm__ volatile("s_waitcnt vmcnt(0)" ::: "memory"); }
        __builtin_amdgcn_s_barrier();
        CLOBBER();

        // (c) QK^T + fused epilogue per 16-col subtile
#pragma unroll
        for (int cs = 0; cs < 4; ++cs) {
            f32x4 acc = (f32x4){0.f, 0.f, 0.f, 0.f};
#pragma unroll
            for (int ks = 0; ks < 2; ++ks) {
                s16x8 bK = *(const s16x8*)&kb[bu][(cs * 2 + ks) * 512 + lane * 8];
                acc = __builtin_amdgcn_mfma_f32_16x16x32_bf16(aQ[ks], bK, acc, 0, 0, 0);
            }
#pragma unroll
            for (int rg = 0; rg < 4; ++rg) {
                const int mv = __builtin_amdgcn_ds_bpermute(
                    (rg * 16 + cs * 4) * 4 + bidx0, (int)um);
                const float t = ((((unsigned)mv) >> bsel) & 1u) ? acc[rg] : 0.0f;
                const float r = floorf(t * rr[rg]);
                lsum += r;
                pw[(quad * 4 + rg) * LDP + cs * 16 + n16] = (short)f2bf(t * r);
            }
        }

        // (d) within-wave LDS drain for pb
        __builtin_amdgcn_wave_barrier();
        __asm__ volatile("s_waitcnt lgkmcnt(0)" ::: "memory");
        __builtin_amdgcn_wave_barrier();

        // (e) PV
#pragma unroll
        for (int ksj = 0; ksj < 2; ++ksj) {
            s16x8 aP = *(const s16x8*)&pw[n16 * LDP + ksj * 32 + quad * 8];
#pragma unroll
            for (int ds = 0; ds < 4; ++ds) {
                s16x8 bV = *(const s16x8*)&vb[bu][(ksj * 4 + ds) * 512 + lane * 8];
                accO[ds] = __builtin_amdgcn_mfma_f32_16x16x32_bf16(aP, bV, accO[ds], 0, 0, 0);
            }
        }

        // (f) all waves done reading [bu] before next tile's (a) DMAs into it
        CLOBBER();
        __builtin_amdgcn_s_barrier();
        CLOBBER();
    }

    // deterministic partial stores (full 64B segments)
    float* op = Opart + (size_t)ic * S * D;
#pragma unroll
    for (int ds = 0; ds < 4; ++ds) {
        const int d = ds * 16 + n16;
#pragma unroll
        for (int rg = 0; rg < 4; ++rg) {
            const int i = i0w + quad * 4 + rg;
            op[(size_t)i * D + d] = accO[ds][rg];
        }
    }

    // sum(r): wave shuffle -> LDS -> one int atomic per block
    for (int off = 32; off; off >>= 1) lsum += __shfl_down(lsum, off);
    if (lane == 0) red[w] = (int)lsum;
    __syncthreads();
    if (tid == 0) atomicAdd(sumr, red[0] + red[1] + red[2] + red[3]);
}

// ---- reduce partials over NCHUNK + apply 1/R ----
__global__ void reduce_out(const float* __restrict__ Opart,
                           const int* __restrict__ sumr,
                           float* __restrict__ out) {
    const int idx = blockIdx.x * 256 + threadIdx.x;   // 65536 float4 groups
    const float invR = 1.0f / (float)(*sumr);         // |R| < 2^24: exact
    float sx = 0.f, sy = 0.f, sz = 0.f, sw = 0.f;
#pragma unroll
    for (int c = 0; c < NCHUNK; ++c) {
        const float4 v = ((const float4*)(Opart + (size_t)c * S * D))[idx];
        sx += v.x; sy += v.y; sz += v.z; sw += v.w;
    }
    float4 o; o.x = sx * invR; o.y = sy * invR; o.z = sz * invR; o.w = sw * invR;
    ((float4*)out)[idx] = o;
}

extern "C" void kernel_launch(void* const* d_in, const int* in_sizes, int n_in,
                              void* d_out, int out_size, void* d_ws, size_t ws_size,
                              hipStream_t stream) {
    (void)in_sizes; (void)n_in; (void)out_size; (void)ws_size;
    const float* Q  = (const float*)d_in[0];
    const float* Kf = (const float*)d_in[1];
    const float* V  = (const float*)d_in[2];
    const float* Ud = (const float*)d_in[3];
    const float* RR = (const float*)d_in[4];
    float* out = (float*)d_out;

    // ws layout: Opart 16MB | Qbf 512KB | Kbf 512KB | VTbf 512KB | sumr
    char* ws = (char*)d_ws;
    float* Opart = (float*)ws;                                  // 16 MB
    short* Qbf  = (short*)(ws + (16u << 20));
    short* Kbf  = (short*)(ws + (16u << 20) + (512u << 10));
    short* VTbf = (short*)(ws + (16u << 20) + (1024u << 10));
    int*   sumr = (int*)  (ws + (16u << 20) + (1536u << 10));

    prep_all<<<dim3(576), dim3(256), 0, stream>>>(Q, Kf, V, Qbf, Kbf, VTbf, sumr);
    fused_main<<<dim3(64 * NCHUNK), dim3(256), 0, stream>>>(
        Qbf, Kbf, VTbf, Ud, RR, Opart, sumr);
    reduce_out<<<dim3(256), dim3(256), 0, stream>>>(Opart, sumr, out);
}

// Round 15
// 121.299 us; speedup vs baseline: 1.0498x; 1.0498x over previous
//
#include <hip/hip_runtime.h>
#include <stdint.h>

// S=4096, D=64.  out = (t * floor(t*rr)/R) @ V,  t = (QK^T*8) * dropout_keep/0.9
// R15 = R12 (best measured: 120.75us; NCHUNK=8, JT=128, kb dbuf, vb single,
// DMA staging, fragment-major LDS, counted vmcnt, raw s_barrier) + asm memory
// clobbers pinning EVERY vmem group. R13 proved the compiler can hoist plain
// u-loads across a global_load_lds DMA, permuting the vmcnt queue and breaking
// the counted gate; R12 shipped with that latent hole ((g) V-DMA -> next (a)
// u-loads unpinned). This round closes it with zero intended perf change.

#define S 4096
#define D 64
#define NCHUNK 8              // grid = 64 i-blocks * 8 chunks = 512 blocks
#define JCHUNK (S / NCHUNK)   // 512
#define JT 128
#define NTILES (JCHUNK / JT)  // 4
#define LDP 132               // pb pitch (shorts)
#define KSCALE (8.0f / 0.9f)

typedef float f32x4 __attribute__((ext_vector_type(4)));
typedef short s16x8 __attribute__((ext_vector_type(8)));
typedef unsigned short u16x4 __attribute__((ext_vector_type(4)));
typedef const __attribute__((address_space(1))) unsigned g_u32;
typedef __attribute__((address_space(3))) unsigned lds_u32;

#define CLOBBER() __asm__ volatile("" ::: "memory")

__device__ inline unsigned short f2bf(float f) {
    union { float f; unsigned u; } v; v.f = f;
    unsigned r = v.u + 0x7fffu + ((v.u >> 16) & 1u);
    return (unsigned short)(r >> 16);
}

// ---- prep: Q->bf16, K->bf16*KSCALE (blocks 0..511), V->V^T (512..575) ----
__global__ void prep_all(const float* __restrict__ Q,
                         const float* __restrict__ Kf,
                         const float* __restrict__ V,
                         short* __restrict__ Qbf, short* __restrict__ Kbf,
                         short* __restrict__ VTbf, int* __restrict__ sumr) {
    __shared__ short tile[64 * 68];
    const int b   = blockIdx.x;
    const int tid = threadIdx.x;
    if (b == 0 && tid == 0) *sumr = 0;

    if (b < 512) {
        const int idx = b * 256 + tid;               // 131072 float4 slots
        if (idx < 65536) {
            float4 v = ((const float4*)Q)[idx];
            u16x4 o; o[0] = f2bf(v.x); o[1] = f2bf(v.y); o[2] = f2bf(v.z); o[3] = f2bf(v.w);
            ((u16x4*)Qbf)[idx] = o;
        } else {
            const int k = idx - 65536;
            float4 v = ((const float4*)Kf)[k];
            u16x4 o; o[0] = f2bf(v.x * KSCALE); o[1] = f2bf(v.y * KSCALE);
                     o[2] = f2bf(v.z * KSCALE); o[3] = f2bf(v.w * KSCALE);
            ((u16x4*)Kbf)[k] = o;
        }
    } else {
        const int j0 = (b - 512) * 64;
#pragma unroll
        for (int it = 0; it < 4; ++it) {
            const int f4 = tid + it * 256;
            const int row = f4 >> 4, c4 = (f4 & 15) * 4;
            float4 v = *(const float4*)&V[(size_t)(j0 + row) * D + c4];
            tile[(c4 + 0) * 68 + row] = (short)f2bf(v.x);
            tile[(c4 + 1) * 68 + row] = (short)f2bf(v.y);
            tile[(c4 + 2) * 68 + row] = (short)f2bf(v.z);
            tile[(c4 + 3) * 68 + row] = (short)f2bf(v.w);
        }
        __syncthreads();
#pragma unroll
        for (int it = 0; it < 4; ++it) {
            const int f4 = tid + it * 256;
            const int d = f4 >> 4, o4 = (f4 & 15) * 4;
            u16x4 w = *(const u16x4*)&tile[d * 68 + o4];
            *(u16x4*)&VTbf[(size_t)d * S + j0 + o4] = w;
        }
    }
}

// ---- main ----
__launch_bounds__(256, 2)
__global__ void fused_main(const short* __restrict__ Qbf,
                           const short* __restrict__ Kbf,
                           const short* __restrict__ VTbf,
                           const float* __restrict__ Ud,
                           const float* __restrict__ RR,
                           float* __restrict__ Opart,            // [NCHUNK][S][D]
                           int* __restrict__ sumr)
{
    __shared__ short kb[2][16 * 512];    // K tile 128x64, fragment-major, dbuf
    __shared__ short vb[16 * 512];       // V^T tile 64x128, fragment-major, SINGLE
    __shared__ short pb[4 * 16 * LDP];   // per-wave P relayout (16 x 128)
    __shared__ int red[4];

    const int tid  = threadIdx.x;
    const int w    = tid >> 6;
    const int lane = tid & 63;
    const int quad = lane >> 4;
    const int n16  = lane & 15;

    const int ib  = blockIdx.x & 63;
    const int ic  = blockIdx.x >> 6;     // 0..NCHUNK-1
    const int i0w = ib * 64 + w * 16;
    const int jbase = ic * JCHUNK;

    const float* uwb = Ud + (size_t)i0w * S;

    s16x8 aQ[2];
#pragma unroll
    for (int ks = 0; ks < 2; ++ks)
        aQ[ks] = *(const s16x8*)&Qbf[(size_t)(i0w + n16) * D + ks * 32 + quad * 8];

    float rr[4];
#pragma unroll
    for (int rg = 0; rg < 4; ++rg) rr[rg] = RR[i0w + quad * 4 + rg];

    f32x4 accO[4];
#pragma unroll
    for (int ds = 0; ds < 4; ++ds) accO[ds] = (f32x4){0.f, 0.f, 0.f, 0.f};

    float lsum = 0.f;
    short* pw = pb + w * 16 * LDP;

    unsigned um[2];                        // 32 keep-bits per lane per tile
    const int bsel  = quad * 4 + (n16 & 3);      // + h*16 at use
    const int bidx0 = (n16 >> 2) * 4;

    // ---- prologue: tile 0 (u first | K-DMA | V-DMA; each group pinned) ----
    float4 un[8];
    {
        const int j0 = jbase;
#pragma unroll
        for (int h = 0; h < 2; ++h)
#pragma unroll
            for (int q = 0; q < 4; ++q)
                un[h * 4 + q] = *(const float4*)&uwb[(size_t)(q * 4 + quad) * S + j0 + h * 64 + n16 * 4];
        CLOBBER();
#pragma unroll
        for (int p = 0; p < 4; ++p) {
            const int e = w * 4 + p;
            __builtin_amdgcn_global_load_lds(
                (g_u32*)&Kbf[(size_t)(j0 + (e >> 1) * 16 + n16) * D + (e & 1) * 32 + quad * 8],
                (lds_u32*)&kb[0][e * 512], 16, 0, 0);
        }
        CLOBBER();
#pragma unroll
        for (int p = 0; p < 4; ++p) {
            const int e = w * 4 + p;
            __builtin_amdgcn_global_load_lds(
                (g_u32*)&VTbf[(size_t)((e & 3) * 16 + n16) * S + j0 + (e >> 2) * 32 + quad * 8],
                (lds_u32*)&vb[e * 512], 16, 0, 0);
        }
        CLOBBER();
        unsigned m = 0;
#pragma unroll
        for (int e = 0; e < 8; ++e) {   // pack drains u0 only (K0/V0 younger, stay)
            m |= (un[e].x >= 0.1f ? 1u : 0u) << (e * 4 + 0);
            m |= (un[e].y >= 0.1f ? 1u : 0u) << (e * 4 + 1);
            m |= (un[e].z >= 0.1f ? 1u : 0u) << (e * 4 + 2);
            m |= (un[e].w >= 0.1f ? 1u : 0u) << (e * 4 + 3);
        }
        um[0] = m;
    }

#pragma unroll
    for (int jt = 0; jt < NTILES; ++jt) {
        const int bu = jt & 1;
        const int nb = bu ^ 1;
        const int j0 = jbase + jt * JT;
        const bool last = (jt + 1 == NTILES);

        // (a) NEXT tile: u loads (pinned), then K-DMA into kb[nb] (pinned)
        if (!last) {
            const int j1 = j0 + JT;
#pragma unroll
            for (int h = 0; h < 2; ++h)
#pragma unroll
                for (int q = 0; q < 4; ++q)
                    un[h * 4 + q] = *(const float4*)&uwb[(size_t)(q * 4 + quad) * S + j1 + h * 64 + n16 * 4];
            CLOBBER();
#pragma unroll
            for (int p = 0; p < 4; ++p) {
                const int e = w * 4 + p;
                __builtin_amdgcn_global_load_lds(
                    (g_u32*)&Kbf[(size_t)(j1 + (e >> 1) * 16 + n16) * D + (e & 1) * 32 + quad * 8],
                    (lds_u32*)&kb[nb][e * 512], 16, 0, 0);
            }
            CLOBBER();
        }

        // (b) gate: keep the 12 youngest (u(t+1) 8 + K(t+1) 4); drain V(t) etc.
        if (!last) { __asm__ volatile("s_waitcnt vmcnt(12)" ::: "memory"); }
        else       { __asm__ volatile("s_waitcnt vmcnt(0)"  ::: "memory"); }
        __builtin_amdgcn_s_barrier();
        CLOBBER();

        // (c) QK^T + fused epilogue per 16-col subtile
#pragma unroll
        for (int cs = 0; cs < 8; ++cs) {
            f32x4 acc = (f32x4){0.f, 0.f, 0.f, 0.f};
#pragma unroll
            for (int ks = 0; ks < 2; ++ks) {
                s16x8 bK = *(const s16x8*)&kb[bu][(cs * 2 + ks) * 512 + lane * 8];
                acc = __builtin_amdgcn_mfma_f32_16x16x32_bf16(aQ[ks], bK, acc, 0, 0, 0);
            }
            const int h = cs >> 2, c4 = cs & 3;
#pragma unroll
            for (int rg = 0; rg < 4; ++rg) {
                const int mv = __builtin_amdgcn_ds_bpermute(
                    (rg * 16 + c4 * 4) * 4 + bidx0, (int)um[bu]);
                const float t = ((((unsigned)mv) >> (h * 16 + bsel)) & 1u) ? acc[rg] : 0.0f;
                const float r = floorf(t * rr[rg]);
                lsum += r;
                pw[(quad * 4 + rg) * LDP + cs * 16 + n16] = (short)f2bf(t * r);
            }
        }

        // (d) within-wave LDS drain for pb
        __builtin_amdgcn_wave_barrier();
        __asm__ volatile("s_waitcnt lgkmcnt(0)" ::: "memory");
        __builtin_amdgcn_wave_barrier();

        // (e) PV over 128-wide contraction
#pragma unroll
        for (int ksj = 0; ksj < 4; ++ksj) {
            s16x8 aP = *(const s16x8*)&pw[n16 * LDP + ksj * 32 + quad * 8];
#pragma unroll
            for (int ds = 0; ds < 4; ++ds) {
                s16x8 bV = *(const s16x8*)&vb[(ksj * 4 + ds) * 512 + lane * 8];
                accO[ds] = __builtin_amdgcn_mfma_f32_16x16x32_bf16(aP, bV, accO[ds], 0, 0, 0);
            }
        }

        // (f) all waves past PV before vb is overwritten
        CLOBBER();
        __builtin_amdgcn_s_barrier();
        CLOBBER();

        // (g) pack u(t+1) (drains u(t+1), keeps K(t+1)), then V(t+1) into vb —
        //     V-DMA group PINNED so next (a)'s u-loads cannot hoist above it
        //     (the R13 failure mode).
        if (!last) {
            unsigned m = 0;
#pragma unroll
            for (int e = 0; e < 8; ++e) {
                m |= (un[e].x >= 0.1f ? 1u : 0u) << (e * 4 + 0);
                m |= (un[e].y >= 0.1f ? 1u : 0u) << (e * 4 + 1);
                m |= (un[e].z >= 0.1f ? 1u : 0u) << (e * 4 + 2);
                m |= (un[e].w >= 0.1f ? 1u : 0u) << (e * 4 + 3);
            }
            um[nb] = m;
            const int j1 = j0 + JT;
            CLOBBER();
#pragma unroll
            for (int p = 0; p < 4; ++p) {
                const int e = w * 4 + p;
                __builtin_amdgcn_global_load_lds(
                    (g_u32*)&VTbf[(size_t)((e & 3) * 16 + n16) * S + j1 + (e >> 2) * 32 + quad * 8],
                    (lds_u32*)&vb[e * 512], 16, 0, 0);
            }
            CLOBBER();
        }
    }

    // deterministic partial stores (full 64B segments)
    float* op = Opart + (size_t)ic * S * D;
#pragma unroll
    for (int ds = 0; ds < 4; ++ds) {
        const int d = ds * 16 + n16;
#pragma unroll
        for (int rg = 0; rg < 4; ++rg) {
            const int i = i0w + quad * 4 + rg;
            op[(size_t)i * D + d] = accO[ds][rg];
        }
    }

    // sum(r): wave shuffle -> LDS -> one int atomic per block
    for (int off = 32; off; off >>= 1) lsum += __shfl_down(lsum, off);
    if (lane == 0) red[w] = (int)lsum;
    __syncthreads();
    if (tid == 0) atomicAdd(sumr, red[0] + red[1] + red[2] + red[3]);
}

// ---- reduce partials over NCHUNK + apply 1/R ----
__global__ void reduce_out(const float* __restrict__ Opart,
                           const int* __restrict__ sumr,
                           float* __restrict__ out) {
    const int idx = blockIdx.x * 256 + threadIdx.x;   // 65536 float4 groups
    const float invR = 1.0f / (float)(*sumr);         // |R| < 2^24: exact
    float sx = 0.f, sy = 0.f, sz = 0.f, sw = 0.f;
#pragma unroll
    for (int c = 0; c < NCHUNK; ++c) {
        const float4 v = ((const float4*)(Opart + (size_t)c * S * D))[idx];
        sx += v.x; sy += v.y; sz += v.z; sw += v.w;
    }
    float4 o; o.x = sx * invR; o.y = sy * invR; o.z = sz * invR; o.w = sw * invR;
    ((float4*)out)[idx] = o;
}

extern "C" void kernel_launch(void* const* d_in, const int* in_sizes, int n_in,
                              void* d_out, int out_size, void* d_ws, size_t ws_size,
                              hipStream_t stream) {
    (void)in_sizes; (void)n_in; (void)out_size; (void)ws_size;
    const float* Q  = (const float*)d_in[0];
    const float* Kf = (const float*)d_in[1];
    const float* V  = (const float*)d_in[2];
    const float* Ud = (const float*)d_in[3];
    const float* RR = (const float*)d_in[4];
    float* out = (float*)d_out;

    // ws layout: Opart 8MB | Qbf 512KB | Kbf 512KB | VTbf 512KB | sumr
    char* ws = (char*)d_ws;
    float* Opart = (float*)ws;                                  // 8 MB
    short* Qbf  = (short*)(ws + (8u << 20));
    short* Kbf  = (short*)(ws + (8u << 20) + (512u << 10));
    short* VTbf = (short*)(ws + (8u << 20) + (1024u << 10));
    int*   sumr = (int*)  (ws + (8u << 20) + (1536u << 10));

    prep_all<<<dim3(576), dim3(256), 0, stream>>>(Q, Kf, V, Qbf, Kbf, VTbf, sumr);
    fused_main<<<dim3(64 * NCHUNK), dim3(256), 0, stream>>>(
        Qbf, Kbf, VTbf, Ud, RR, Opart, sumr);
    reduce_out<<<dim3(256), dim3(256), 0, stream>>>(Opart, sumr, out);
}